// Round 1
// baseline (372.649 us; speedup 1.0000x reference)
//
#include <hip/hip_runtime.h>

#define NN 4096
#define DD 256
#define EE 131072

typedef __attribute__((ext_vector_type(8))) short s16x8;
typedef __attribute__((ext_vector_type(4))) float f32x4;

__device__ __forceinline__ unsigned short f2bf(float f) {
  unsigned u = __builtin_bit_cast(unsigned, f);
  u += 0x7FFFu + ((u >> 16) & 1u);
  return (unsigned short)(u >> 16);
}

__device__ __forceinline__ ushort4 cvt4(f32x4 v) {
  ushort4 r;
  r.x = f2bf(v[0]); r.y = f2bf(v[1]); r.z = f2bf(v[2]); r.w = f2bf(v[3]);
  return r;
}

// ---------------------------------------------------------------------------
// K1: count in-degrees (atomic, int) + transpose/convert both weight matrices
//     grid 1024 x 256: threads [0,EE) count edges; [EE, EE+2*65536) transpose.
// ---------------------------------------------------------------------------
__global__ void k_count_wt(const int* __restrict__ ei, int* __restrict__ deg,
                           const float* __restrict__ Wh, const float* __restrict__ Wc,
                           unsigned short* __restrict__ Wth, unsigned short* __restrict__ Wtc) {
  int t = blockIdx.x * 256 + threadIdx.x;
  if (t < EE) {
    int d = ei[EE + t];
    atomicAdd(&deg[d], 1);
  } else {
    int idx = t - EE;                  // 0..131071
    int which = idx >> 16;             // 0: W_high, 1: W_conv
    int r = idx & 65535;
    int n = r >> 8, k = r & 255;
    const float* W = which ? Wc : Wh;
    unsigned short* Wt = which ? Wtc : Wth;
    Wt[(n << 8) + k] = f2bf(W[(k << 8) + n]);   // Wt[n][k] = W[k][n]
  }
}

// ---------------------------------------------------------------------------
// K2: exclusive scan of deg (4096) -> row_start[4097]; dis = rsqrt(deg+1)
//     single block, 1024 threads, 4 elems/thread
// ---------------------------------------------------------------------------
__global__ void k_scan(const int* __restrict__ deg, int* __restrict__ row_start,
                       float* __restrict__ dis) {
  __shared__ int part[1024];
  int t = threadIdx.x;
  int d0 = deg[4 * t + 0], d1 = deg[4 * t + 1], d2 = deg[4 * t + 2], d3 = deg[4 * t + 3];
  int s = d0 + d1 + d2 + d3;
  part[t] = s;
  __syncthreads();
  for (int off = 1; off < 1024; off <<= 1) {
    int add = (t >= off) ? part[t - off] : 0;
    __syncthreads();
    part[t] += add;
    __syncthreads();
  }
  int base = part[t] - s;   // exclusive prefix of this thread's group
  row_start[4 * t + 0] = base;
  row_start[4 * t + 1] = base + d0;
  row_start[4 * t + 2] = base + d0 + d1;
  row_start[4 * t + 3] = base + d0 + d1 + d2;
  if (t == 1023) row_start[4096] = part[t];
  dis[4 * t + 0] = rsqrtf((float)d0 + 1.0f);
  dis[4 * t + 1] = rsqrtf((float)d1 + 1.0f);
  dis[4 * t + 2] = rsqrtf((float)d2 + 1.0f);
  dis[4 * t + 3] = rsqrtf((float)d3 + 1.0f);
}

// ---------------------------------------------------------------------------
// K3: scatter edges into CSR buckets
// ---------------------------------------------------------------------------
__global__ void k_scatter(const int* __restrict__ ei, const int* __restrict__ row_start,
                          int* __restrict__ cursor, int* __restrict__ csr) {
  int e = blockIdx.x * 256 + threadIdx.x;
  if (e < EE) {
    int s = ei[e];
    int d = ei[EE + e];
    int p = atomicAdd(&cursor[d], 1);
    csr[row_start[d] + p] = s;
  }
}

// ---------------------------------------------------------------------------
// K4: dual small matmul: Rt = relu(x @ W_high)^T (bf16, [DD][NN])
//                        XWc = x @ W_conv        (fp32, [NN][DD])
//     grid 256 (M-tiles of 16), block 512 (8 waves). waves 0-3: high, 4-7: conv.
// ---------------------------------------------------------------------------
__global__ __launch_bounds__(512) void k_xw(const float* __restrict__ x,
                                            const unsigned short* __restrict__ Wth,
                                            const unsigned short* __restrict__ Wtc,
                                            unsigned short* __restrict__ Rt,
                                            float* __restrict__ XWc) {
  __shared__ unsigned short Abuf[16][264];   // stride 264: 2-way bank alias only
  const int tid = threadIdx.x;
  const int w = tid >> 6, lane = tid & 63;
  const int quad = lane >> 4, l16 = lane & 15;
  const int quad8 = quad * 8;
  const int m0 = blockIdx.x * 16;

  // stage A tile 16x256 fp32 -> bf16 LDS (8 elems/thread)
  {
    int srow = tid >> 5, scol = (tid & 31) * 8;
    const float* ap = x + (long)(m0 + srow) * DD + scol;
    f32x4 a0 = *(const f32x4*)ap;
    f32x4 a1 = *(const f32x4*)(ap + 4);
    *(ushort4*)&Abuf[srow][scol] = cvt4(a0);
    *(ushort4*)&Abuf[srow][scol + 4] = cvt4(a1);
  }
  __syncthreads();

  const bool hi = (w < 4);
  const int wo = hi ? w : (w - 4);
  const unsigned short* Bt = hi ? Wth : Wtc;
  const unsigned short* bp = Bt + (long)(64 * wo + l16) * DD + quad8;

  f32x4 acc[4] = {{0,0,0,0},{0,0,0,0},{0,0,0,0},{0,0,0,0}};
#pragma unroll
  for (int q = 0; q < 8; ++q) {
    s16x8 af = *(const s16x8*)&Abuf[l16][q * 32 + quad8];
#pragma unroll
    for (int s = 0; s < 4; ++s) {
      s16x8 bf = *(const s16x8*)(bp + s * 16 * DD + q * 32);
      acc[s] = __builtin_amdgcn_mfma_f32_16x16x32_bf16(af, bf, acc[s], 0, 0, 0);
    }
  }

  if (hi) {
    // relu -> bf16 -> transposed store: Rt[n][m], 4 consecutive m per lane (8B)
#pragma unroll
    for (int s = 0; s < 4; ++s) {
      int n_g = 64 * wo + 16 * s + l16;
      f32x4 v = acc[s];
      f32x4 z;
      z[0] = v[0] > 0.f ? v[0] : 0.f;
      z[1] = v[1] > 0.f ? v[1] : 0.f;
      z[2] = v[2] > 0.f ? v[2] : 0.f;
      z[3] = v[3] > 0.f ? v[3] : 0.f;
      *(ushort4*)(Rt + (long)n_g * NN + m0 + quad * 4) = cvt4(z);
    }
  } else {
    // fp32 normal store: XWc[m][n]
#pragma unroll
    for (int s = 0; s < 4; ++s) {
      int col = 64 * wo + 16 * s + l16;
#pragma unroll
      for (int r = 0; r < 4; ++r) {
        XWc[(long)(m0 + quad * 4 + r) * DD + col] = acc[s][r];
      }
    }
  }
}

// ---------------------------------------------------------------------------
// K5: GCN aggregation via CSR gather (no atomics)
//     Hl[i][j] = dis[i] * ( dis[i]*xwc[i][j] + sum_{s in N(i)} dis[s]*xwc[s][j] )
//     grid 4096 (node per block), block 256 (col per thread)
// ---------------------------------------------------------------------------
__global__ void k_agg(const float* __restrict__ XWc, const int* __restrict__ row_start,
                      const int* __restrict__ csr, const float* __restrict__ dis,
                      float* __restrict__ Hl) {
  const int i = blockIdx.x;
  const int t = threadIdx.x;
  const int b0 = row_start[i], b1 = row_start[i + 1];
  const float di = dis[i];
  float acc = di * XWc[(long)i * DD + t];    // self loop (one factor of di applied at end)
  for (int j = b0; j < b1; ++j) {
    int s = csr[j];
    acc += dis[s] * XWc[(long)s * DD + t];
  }
  Hl[(long)i * DD + t] = di * acc;
}

// ---------------------------------------------------------------------------
// K6: big matmul C[NN x DD] = A[NN x NN] @ B, with B given transposed as
//     Bt[DD][NN] bf16. grid 256 (16-row M-tile), block 512 (8 waves x 2 N-tiles).
//     A staged fp32->bf16 through LDS (double-buffered, depth-2 prefetch);
//     B fragments loaded directly global->VGPR (L2-resident, 2 MB).
//     EPI 0: store C^T bf16 to outT [DD][NN]
//     EPI 3: out fp32 [NN][DD] = aH*C + aL*(Hl + b_conv)   (final fused epilogue)
// ---------------------------------------------------------------------------
#define MM_STEP(c, CUR, NXT)                                                     \
  {                                                                              \
    f32x4 afut = anext;                                                          \
    if ((c) + 2 < 32) afut = *(const f32x4*)(aptr + ((c) + 2) * 128);            \
    if ((c) + 1 < 32) {                                                          \
      _Pragma("unroll")                                                          \
      for (int q = 0; q < 4; ++q) {                                              \
        bb[NXT][0][q] = *(const s16x8*)(bptr0 + ((c) + 1) * 128 + q * 32);       \
        bb[NXT][1][q] = *(const s16x8*)(bptr1 + ((c) + 1) * 128 + q * 32);       \
      }                                                                          \
    }                                                                            \
    _Pragma("unroll")                                                            \
    for (int q = 0; q < 4; ++q) {                                                \
      s16x8 af = *(const s16x8*)&Abuf[CUR][l16][q * 32 + quad8];                 \
      acc[0] = __builtin_amdgcn_mfma_f32_16x16x32_bf16(af, bb[CUR][0][q], acc[0], 0, 0, 0); \
      acc[1] = __builtin_amdgcn_mfma_f32_16x16x32_bf16(af, bb[CUR][1][q], acc[1], 0, 0, 0); \
    }                                                                            \
    if ((c) + 1 < 32) *(ushort4*)&Abuf[NXT][srow][scol] = cvt4(anext);           \
    __syncthreads();                                                             \
    anext = afut;                                                                \
  }

template <int EPI>
__global__ __launch_bounds__(512) void k_mm_big(const float* __restrict__ A,
                                                const unsigned short* __restrict__ Bt,
                                                unsigned short* __restrict__ outT,
                                                float* __restrict__ outF,
                                                const float* __restrict__ Hl,
                                                const float* __restrict__ bconv,
                                                const float* __restrict__ aLp,
                                                const float* __restrict__ aHp) {
  __shared__ unsigned short Abuf[2][16][136];   // stride 136: 2-way bank alias only
  const int tid = threadIdx.x;
  const int w = tid >> 6, lane = tid & 63;
  const int quad = lane >> 4, l16 = lane & 15;
  const int quad8 = quad * 8;
  const int m0 = blockIdx.x * 16;

  const int srow = tid >> 5;          // 0..15
  const int scol = (tid & 31) * 4;    // 0..124
  const float* aptr = A + (long)(m0 + srow) * NN + scol;

  const unsigned short* bptr0 = Bt + (long)(32 * w + l16) * NN + quad8;
  const unsigned short* bptr1 = bptr0 + (long)16 * NN;

  f32x4 acc[2] = {{0,0,0,0},{0,0,0,0}};
  s16x8 bb[2][2][4];

  // prologue: B chunk 0, A chunk 0 staged, A chunk 1 in regs
#pragma unroll
  for (int q = 0; q < 4; ++q) {
    bb[0][0][q] = *(const s16x8*)(bptr0 + q * 32);
    bb[0][1][q] = *(const s16x8*)(bptr1 + q * 32);
  }
  {
    f32x4 a0 = *(const f32x4*)aptr;
    *(ushort4*)&Abuf[0][srow][scol] = cvt4(a0);
  }
  f32x4 anext = *(const f32x4*)(aptr + 128);
  __syncthreads();

  for (int cc = 0; cc < 16; ++cc) {
    MM_STEP(2 * cc, 0, 1)
    MM_STEP(2 * cc + 1, 1, 0)
  }

  if constexpr (EPI == 0) {
    // C/D layout: col = l16, row = quad*4 + reg  ->  outT[n][m], 8B per lane
#pragma unroll
    for (int s = 0; s < 2; ++s) {
      int n_g = 32 * w + 16 * s + l16;
      *(ushort4*)(outT + (long)n_g * NN + m0 + quad * 4) = cvt4(acc[s]);
    }
  } else {
    __shared__ float obuf[16][260];
#pragma unroll
    for (int s = 0; s < 2; ++s) {
      int col = 32 * w + 16 * s + l16;
#pragma unroll
      for (int r = 0; r < 4; ++r) obuf[quad * 4 + r][col] = acc[s][r];
    }
    __syncthreads();
    const float aLv = aLp[0], aHv = aHp[0];
    const int orow = tid >> 5;
    const int ocol = (tid & 31) * 8;
#pragma unroll
    for (int j = 0; j < 2; ++j) {
      f32x4 c = *(const f32x4*)&obuf[orow][ocol + 4 * j];
      f32x4 h = *(const f32x4*)(Hl + (long)(m0 + orow) * DD + ocol + 4 * j);
      f32x4 bc = *(const f32x4*)(bconv + ocol + 4 * j);
      f32x4 res = aHv * c + aLv * (h + bc);
      *(f32x4*)(outF + (long)(m0 + orow) * DD + ocol + 4 * j) = res;
    }
  }
}

// ---------------------------------------------------------------------------
// launcher
// ---------------------------------------------------------------------------
extern "C" void kernel_launch(void* const* d_in, const int* in_sizes, int n_in,
                              void* d_out, int out_size, void* d_ws, size_t ws_size,
                              hipStream_t stream) {
  const float* x     = (const float*)d_in[0];
  const int*   ei    = (const int*)d_in[1];
  const float* lap   = (const float*)d_in[2];
  const float* dinv  = (const float*)d_in[3];
  const float* Wh    = (const float*)d_in[4];
  const float* Wc    = (const float*)d_in[5];
  const float* bconv = (const float*)d_in[6];
  const float* aL    = (const float*)d_in[7];
  const float* aH    = (const float*)d_in[8];
  float* out = (float*)d_out;
  char* ws = (char*)d_ws;

  int* deg        = (int*)(ws);                         // 16 KB
  int* cursor     = (int*)(ws + (16 << 10));            // 16 KB
  int* row_start  = (int*)(ws + (32 << 10));            // 16.4 KB
  int* csr        = (int*)(ws + (64 << 10));            // 512 KB
  float* dis      = (float*)(ws + (576 << 10));         // 16 KB
  unsigned short* Wth = (unsigned short*)(ws + (1 << 20));              // 128 KB
  unsigned short* Wtc = (unsigned short*)(ws + (1 << 20) + (128 << 10));// 128 KB
  unsigned short* Rt  = (unsigned short*)(ws + (2l << 20));  // 2 MB  [DD][NN]
  unsigned short* T1t = (unsigned short*)(ws + (4l << 20));  // 2 MB
  unsigned short* T2t = (unsigned short*)(ws + (6l << 20));  // 2 MB
  float* XWc = (float*)(ws + (8l << 20));                    // 4 MB  [NN][DD]
  float* Hl  = (float*)(ws + (12l << 20));                   // 4 MB  [NN][DD]

  hipMemsetAsync(ws, 0, 32 << 10, stream);   // deg + cursor

  k_count_wt<<<1024, 256, 0, stream>>>(ei, deg, Wh, Wc, Wth, Wtc);
  k_scan<<<1, 1024, 0, stream>>>(deg, row_start, dis);
  k_scatter<<<512, 256, 0, stream>>>(ei, row_start, cursor, csr);
  k_xw<<<256, 512, 0, stream>>>(x, Wth, Wtc, Rt, XWc);
  k_agg<<<4096, 256, 0, stream>>>(XWc, row_start, csr, dis, Hl);

  // Hh chain: T1 = d_inv @ R ; T2 = lap @ T1 ; out = aH*(d_inv @ T2) + aL*(Hl+b)
  k_mm_big<0><<<256, 512, 0, stream>>>(dinv, Rt, T1t, nullptr, nullptr, nullptr, nullptr, nullptr);
  k_mm_big<0><<<256, 512, 0, stream>>>(lap, T1t, T2t, nullptr, nullptr, nullptr, nullptr, nullptr);
  k_mm_big<3><<<256, 512, 0, stream>>>(dinv, T2t, nullptr, out, Hl, bconv, aL, aH);
}

// Round 2
// 273.896 us; speedup vs baseline: 1.3605x; 1.3605x over previous
//
#include <hip/hip_runtime.h>

#define NN 4096
#define DD 256
#define EE 131072

typedef __attribute__((ext_vector_type(8))) short s16x8;
typedef __attribute__((ext_vector_type(4))) float f32x4;

__device__ __forceinline__ unsigned short f2bf(float f) {
  unsigned u = __builtin_bit_cast(unsigned, f);
  u += 0x7FFFu + ((u >> 16) & 1u);
  return (unsigned short)(u >> 16);
}

__device__ __forceinline__ ushort4 cvt4(f32x4 v) {
  ushort4 r;
  r.x = f2bf(v[0]); r.y = f2bf(v[1]); r.z = f2bf(v[2]); r.w = f2bf(v[3]);
  return r;
}

// round-half-up fp32->bf16 pair pack: 2 adds + 1 v_perm
__device__ __forceinline__ unsigned cvt2_rhu(float a, float b) {
  unsigned ua = __builtin_bit_cast(unsigned, a) + 0x8000u;
  unsigned ub = __builtin_bit_cast(unsigned, b) + 0x8000u;
  return __builtin_amdgcn_perm(ub, ua, 0x07060302u);
}

__device__ __forceinline__ uint4 pack8(f32x4 a, f32x4 b) {
  uint4 r;
  r.x = cvt2_rhu(a[0], a[1]); r.y = cvt2_rhu(a[2], a[3]);
  r.z = cvt2_rhu(b[0], b[1]); r.w = cvt2_rhu(b[2], b[3]);
  return r;
}

// B fragment layout (consumed by mfma_16x16x32_bf16 B-operand):
//   element (n, k) of a 256-col operand lives at ushort index
//   (tile*NCHUNK + kc)*512 + (quad*16 + (n&15))*8 + (k&7)
//   tile = n>>4, kc = k>>5, quad = (k>>3)&3.  One wave chunk-load = 1KB coalesced.

// ---------------------------------------------------------------------------
// K1: count in-degrees + write both W matrices in B-fragment layout (bf16)
// ---------------------------------------------------------------------------
__global__ void k_prep(const int* __restrict__ ei, int* __restrict__ deg,
                       const float* __restrict__ Wh, const float* __restrict__ Wc,
                       unsigned short* __restrict__ WFh, unsigned short* __restrict__ WFc) {
  int t = blockIdx.x * 256 + threadIdx.x;
  if (t < EE) {
    atomicAdd(&deg[ei[EE + t]], 1);
  } else {
    int idx = t - EE;                 // 0..131071
    int which = idx >> 16;            // 0: W_high, 1: W_conv
    int r = idx & 65535;
    int n = r & 255, k = r >> 8;      // consecutive threads -> consecutive n (coalesced read)
    const float* W = which ? Wc : Wh;
    unsigned short* WF = which ? WFc : WFh;
    long fidx = ((long)((n >> 4) * 8 + (k >> 5))) * 512 +
                (((k >> 3) & 3) * 16 + (n & 15)) * 8 + (k & 7);
    WF[fidx] = f2bf(W[k * 256 + n]);  // fragment(n,k) = W[k][n]
  }
}

// ---------------------------------------------------------------------------
// K2: exclusive scan of deg -> row_start[4097]; dis = rsqrt(deg+1)
// ---------------------------------------------------------------------------
__global__ void k_scan(const int* __restrict__ deg, int* __restrict__ row_start,
                       float* __restrict__ dis) {
  __shared__ int part[1024];
  int t = threadIdx.x;
  int d0 = deg[4 * t + 0], d1 = deg[4 * t + 1], d2 = deg[4 * t + 2], d3 = deg[4 * t + 3];
  int s = d0 + d1 + d2 + d3;
  part[t] = s;
  __syncthreads();
  for (int off = 1; off < 1024; off <<= 1) {
    int add = (t >= off) ? part[t - off] : 0;
    __syncthreads();
    part[t] += add;
    __syncthreads();
  }
  int base = part[t] - s;
  row_start[4 * t + 0] = base;
  row_start[4 * t + 1] = base + d0;
  row_start[4 * t + 2] = base + d0 + d1;
  row_start[4 * t + 3] = base + d0 + d1 + d2;
  if (t == 1023) row_start[4096] = part[t];
  dis[4 * t + 0] = rsqrtf((float)d0 + 1.0f);
  dis[4 * t + 1] = rsqrtf((float)d1 + 1.0f);
  dis[4 * t + 2] = rsqrtf((float)d2 + 1.0f);
  dis[4 * t + 3] = rsqrtf((float)d3 + 1.0f);
}

// ---------------------------------------------------------------------------
// K3: scatter edges into CSR buckets
// ---------------------------------------------------------------------------
__global__ void k_scatter(const int* __restrict__ ei, const int* __restrict__ row_start,
                          int* __restrict__ cursor, int* __restrict__ csr) {
  int e = blockIdx.x * 256 + threadIdx.x;
  if (e < EE) {
    int s = ei[e];
    int d = ei[EE + e];
    int p = atomicAdd(&cursor[d], 1);
    csr[row_start[d] + p] = s;
  }
}

// ---------------------------------------------------------------------------
// K4: RF = frag(relu(x @ W_high))  and  XWs[m][n] = dis[m] * (x @ W_conv)[m][n]
//     grid 256 (16-row M-tiles), block 512. waves 0-3: high, 4-7: conv.
//     All B loads are coalesced 1KB fragment loads.
// ---------------------------------------------------------------------------
__global__ __launch_bounds__(512) void k_xw(const float* __restrict__ x,
                                            const unsigned short* __restrict__ WFh,
                                            const unsigned short* __restrict__ WFc,
                                            unsigned short* __restrict__ RF,
                                            float* __restrict__ XWs,
                                            const float* __restrict__ dis) {
  __shared__ alignas(16) unsigned short Abuf[16][264];
  const int tid = threadIdx.x;
  const int w = tid >> 6, lane = tid & 63;
  const int quad = lane >> 4, l16 = lane & 15, quad8 = quad * 8;
  const int m0 = blockIdx.x * 16;

  {
    int srow = tid >> 5, scolf = (tid & 31) * 8;
    const float* ap = x + (long)(m0 + srow) * DD + scolf;
    f32x4 a0 = *(const f32x4*)ap;
    f32x4 a1 = *(const f32x4*)(ap + 4);
    *(uint4*)&Abuf[srow][scolf] = pack8(a0, a1);
  }
  __syncthreads();

  const bool hi = (w < 4);
  const int wo = hi ? w : (w - 4);
  const unsigned short* WF = hi ? WFh : WFc;
  const unsigned short* bp = WF + lane * 8;

  f32x4 acc[4] = {{0,0,0,0},{0,0,0,0},{0,0,0,0},{0,0,0,0}};
#pragma unroll
  for (int q = 0; q < 8; ++q) {
    s16x8 af = *(const s16x8*)&Abuf[l16][q * 32 + quad8];
#pragma unroll
    for (int s = 0; s < 4; ++s) {
      s16x8 bf = *(const s16x8*)(bp + ((long)((4 * wo + s) * 8 + q)) * 512);
      acc[s] = __builtin_amdgcn_mfma_f32_16x16x32_bf16(af, bf, acc[s], 0, 0, 0);
    }
  }

  if (hi) {
    const int kc = m0 >> 5;
    const int qp = ((m0 >> 4) & 1) * 2 + (quad >> 1);
    const int j0 = (quad & 1) * 4;
#pragma unroll
    for (int s = 0; s < 4; ++s) {
      int t = 4 * wo + s;
      f32x4 v = acc[s];
      f32x4 z;
      z[0] = v[0] > 0.f ? v[0] : 0.f;
      z[1] = v[1] > 0.f ? v[1] : 0.f;
      z[2] = v[2] > 0.f ? v[2] : 0.f;
      z[3] = v[3] > 0.f ? v[3] : 0.f;
      long idx = ((long)(t * 128 + kc)) * 512 + (qp * 16 + l16) * 8 + j0;
      *(ushort4*)(RF + idx) = cvt4(z);
    }
  } else {
    float dm[4];
#pragma unroll
    for (int r = 0; r < 4; ++r) dm[r] = dis[m0 + quad * 4 + r];
#pragma unroll
    for (int s = 0; s < 4; ++s) {
      int col = 64 * wo + 16 * s + l16;
#pragma unroll
      for (int r = 0; r < 4; ++r)
        XWs[(long)(m0 + quad * 4 + r) * DD + col] = dm[r] * acc[s][r];
    }
  }
}

// ---------------------------------------------------------------------------
// K5: GCN aggregation, dis pre-multiplied into XWs; unroll-by-4 gathers
// ---------------------------------------------------------------------------
__global__ void k_agg(const float* __restrict__ XWs, const int* __restrict__ row_start,
                      const int* __restrict__ csr, const float* __restrict__ dis,
                      float* __restrict__ Hl) {
  const int i = blockIdx.x;
  const int t = threadIdx.x;
  const int b0 = row_start[i], b1 = row_start[i + 1];
  float acc = XWs[(long)i * DD + t];   // self loop
  int j = b0;
  for (; j + 4 <= b1; j += 4) {
    int s0 = csr[j], s1 = csr[j + 1], s2 = csr[j + 2], s3 = csr[j + 3];
    float v0 = XWs[(long)s0 * DD + t];
    float v1 = XWs[(long)s1 * DD + t];
    float v2 = XWs[(long)s2 * DD + t];
    float v3 = XWs[(long)s3 * DD + t];
    acc += (v0 + v1) + (v2 + v3);
  }
  for (; j < b1; ++j) acc += XWs[(long)csr[j] * DD + t];
  Hl[(long)i * DD + t] = dis[i] * acc;
}

// ---------------------------------------------------------------------------
// K6: C[4096 x 256] = A[4096 x 4096](fp32) @ B, B in fragment layout (bf16).
//     grid 256: tile = blk&127 (32 rows), half = blk>>7 (128 cols); pairs
//     (i, i+128) share A rows and land on the same XCD (round-robin %8).
//     Block 512 = 8 waves; wave w owns n-tile (half*8+w), 2 M-subtiles.
//     K-stages of 256, double-buffered LDS, depth-2 global prefetch:
//     ~64 MFMA + full A/B streaming between barriers (16 barriers total).
//     EPI 0: write C in fragment layout (next mm's B).  EPI 3: fused final.
// ---------------------------------------------------------------------------
template <int EPI>
__global__ __launch_bounds__(512) void k_mm2(const float* __restrict__ A,
                                             const unsigned short* __restrict__ BF,
                                             unsigned short* __restrict__ CF,
                                             float* __restrict__ outF,
                                             const float* __restrict__ Hl,
                                             const float* __restrict__ bconv,
                                             const float* __restrict__ aLp,
                                             const float* __restrict__ aHp) {
  __shared__ alignas(16) unsigned short Abuf[2][32][264];
  const int tid = threadIdx.x;
  const int w = tid >> 6, lane = tid & 63;
  const int quad = lane >> 4, l16 = lane & 15, quad8 = quad * 8;
  const int tile = blockIdx.x & 127, half = blockIdx.x >> 7;
  const int m0 = tile * 32;
  const int tglob = half * 8 + w;

  const int arow = tid >> 4;           // 0..31
  const int acolf = (tid & 15) * 16;   // 0..240 (floats)
  const float* aptr = A + (long)(m0 + arow) * NN + acolf;

  // prologue: stage 0 -> LDS, stage 1 -> regs
  {
    f32x4 c0 = *(const f32x4*)(aptr + 0);
    f32x4 c1 = *(const f32x4*)(aptr + 4);
    f32x4 c2 = *(const f32x4*)(aptr + 8);
    f32x4 c3 = *(const f32x4*)(aptr + 12);
    *(uint4*)&Abuf[0][arow][acolf] = pack8(c0, c1);
    *(uint4*)&Abuf[0][arow][acolf + 8] = pack8(c2, c3);
  }
  f32x4 anext[4];
#pragma unroll
  for (int i = 0; i < 4; ++i) anext[i] = *(const f32x4*)(aptr + 256 + 4 * i);
  __syncthreads();

  f32x4 acc[2] = {{0,0,0,0},{0,0,0,0}};
  const unsigned short* bbase = BF + ((long)tglob * 128) * 512 + lane * 8;

  for (int s = 0; s < 16; ++s) {
    const int cur = s & 1;
    f32x4 afut[4];
    if (s + 2 < 16) {
#pragma unroll
      for (int i = 0; i < 4; ++i)
        afut[i] = *(const f32x4*)(aptr + (s + 2) * 256 + 4 * i);
    } else {
#pragma unroll
      for (int i = 0; i < 4; ++i) afut[i] = anext[i];
    }

    const unsigned short* bs = bbase + ((long)s * 8) * 512;
#pragma unroll
    for (int c8 = 0; c8 < 8; ++c8) {
      s16x8 bf = *(const s16x8*)(bs + c8 * 512);
      s16x8 a0 = *(const s16x8*)&Abuf[cur][l16][c8 * 32 + quad8];
      s16x8 a1 = *(const s16x8*)&Abuf[cur][16 + l16][c8 * 32 + quad8];
      acc[0] = __builtin_amdgcn_mfma_f32_16x16x32_bf16(a0, bf, acc[0], 0, 0, 0);
      acc[1] = __builtin_amdgcn_mfma_f32_16x16x32_bf16(a1, bf, acc[1], 0, 0, 0);
    }

    if (s + 1 < 16) {
      *(uint4*)&Abuf[1 - cur][arow][acolf] = pack8(anext[0], anext[1]);
      *(uint4*)&Abuf[1 - cur][arow][acolf + 8] = pack8(anext[2], anext[3]);
    }
    __syncthreads();
#pragma unroll
    for (int i = 0; i < 4; ++i) anext[i] = afut[i];
  }

  if constexpr (EPI == 0) {
    const int kc = m0 >> 5;   // = tile
#pragma unroll
    for (int mu = 0; mu < 2; ++mu) {
      int qp = mu * 2 + (quad >> 1);
      int j0 = (quad & 1) * 4;
      long idx = ((long)(tglob * 128 + kc)) * 512 + (qp * 16 + l16) * 8 + j0;
      *(ushort4*)(CF + idx) = cvt4(acc[mu]);
    }
  } else {
    __shared__ float obuf[32][132];
#pragma unroll
    for (int mu = 0; mu < 2; ++mu)
#pragma unroll
      for (int r = 0; r < 4; ++r)
        obuf[mu * 16 + quad * 4 + r][w * 16 + l16] = acc[mu][r];
    __syncthreads();
    const float aLv = aLp[0], aHv = aHp[0];
    const int orow = tid >> 4;
    const int ocol = (tid & 15) * 8;
    const int gcol = half * 128 + ocol;
#pragma unroll
    for (int j = 0; j < 2; ++j) {
      f32x4 cc = *(const f32x4*)&obuf[orow][ocol + 4 * j];
      f32x4 h = *(const f32x4*)(Hl + (long)(m0 + orow) * DD + gcol + 4 * j);
      f32x4 bc = *(const f32x4*)(bconv + gcol + 4 * j);
      f32x4 res;
      res[0] = aHv * cc[0] + aLv * (h[0] + bc[0]);
      res[1] = aHv * cc[1] + aLv * (h[1] + bc[1]);
      res[2] = aHv * cc[2] + aLv * (h[2] + bc[2]);
      res[3] = aHv * cc[3] + aLv * (h[3] + bc[3]);
      *(f32x4*)(outF + (long)(m0 + orow) * DD + gcol + 4 * j) = res;
    }
  }
}

// ---------------------------------------------------------------------------
// launcher
// ---------------------------------------------------------------------------
extern "C" void kernel_launch(void* const* d_in, const int* in_sizes, int n_in,
                              void* d_out, int out_size, void* d_ws, size_t ws_size,
                              hipStream_t stream) {
  const float* x     = (const float*)d_in[0];
  const int*   ei    = (const int*)d_in[1];
  const float* lap   = (const float*)d_in[2];
  const float* dinv  = (const float*)d_in[3];
  const float* Wh    = (const float*)d_in[4];
  const float* Wc    = (const float*)d_in[5];
  const float* bconv = (const float*)d_in[6];
  const float* aL    = (const float*)d_in[7];
  const float* aH    = (const float*)d_in[8];
  float* out = (float*)d_out;
  char* ws = (char*)d_ws;

  int* deg        = (int*)(ws);                          // 16 KB
  int* cursor     = (int*)(ws + (16 << 10));             // 16 KB
  int* row_start  = (int*)(ws + (32 << 10));             // 16.4 KB
  int* csr        = (int*)(ws + (64 << 10));             // 512 KB
  float* dis      = (float*)(ws + (576 << 10));          // 16 KB
  unsigned short* WFh = (unsigned short*)(ws + (1l << 20));               // 128 KB
  unsigned short* WFc = (unsigned short*)(ws + (1l << 20) + (128 << 10)); // 128 KB
  unsigned short* RF  = (unsigned short*)(ws + (2l << 20));  // 2 MB fragment layout
  unsigned short* T1F = (unsigned short*)(ws + (4l << 20));  // 2 MB
  unsigned short* T2F = (unsigned short*)(ws + (6l << 20));  // 2 MB
  float* XWs = (float*)(ws + (8l << 20));                    // 4 MB
  float* Hl  = (float*)(ws + (12l << 20));                   // 4 MB

  hipMemsetAsync(ws, 0, 32 << 10, stream);   // deg + cursor

  k_prep<<<1024, 256, 0, stream>>>(ei, deg, Wh, Wc, WFh, WFc);
  k_scan<<<1, 1024, 0, stream>>>(deg, row_start, dis);
  k_scatter<<<512, 256, 0, stream>>>(ei, row_start, cursor, csr);
  k_xw<<<256, 512, 0, stream>>>(x, WFh, WFc, RF, XWs, dis);
  k_agg<<<4096, 256, 0, stream>>>(XWs, row_start, csr, dis, Hl);

  k_mm2<0><<<256, 512, 0, stream>>>(dinv, RF, T1F, nullptr, nullptr, nullptr, nullptr, nullptr);
  k_mm2<0><<<256, 512, 0, stream>>>(lap, T1F, T2F, nullptr, nullptr, nullptr, nullptr, nullptr);
  k_mm2<3><<<256, 512, 0, stream>>>(dinv, T2F, nullptr, out, Hl, bconv, aL, aH);
}